// Round 16
// baseline (2186.757 us; speedup 1.0000x reference)
//
#include <hip/hip_runtime.h>

typedef __bf16 bf16;
typedef bf16 bf16x8 __attribute__((ext_vector_type(8)));
typedef float f32x4 __attribute__((ext_vector_type(4)));
typedef _Float16 f16;
typedef f16 f16x8 __attribute__((ext_vector_type(8)));

#define NBT 4096      // B*T = 8*512
#define NJ 21
#define NLF 86016     // NBT*NJ (one hand)
#define DD 256
#define CONVM1 86352  // 168*514 (one hand)
#define CONVM2 172704 // both hands
#define SPAD 514
#define CROWS_ALL 173056  // 1 guard + 172704 + slack

// async global->LDS, 16B per lane; LDS dest is WAVE-UNIFORM base + lane*16
__device__ __forceinline__ void gload16(const bf16* g, bf16* l) {
  __builtin_amdgcn_global_load_lds(
      (const __attribute__((address_space(1))) unsigned int*)g,
      (__attribute__((address_space(3))) unsigned int*)l, 16, 0, 0);
}

// flags: 1=A_F32  2=OUT_F32(C32)  4=RELU  8=BNSS(sc/sh)  16=PADZ(conv layout)
//        32=LFOUT(conv row -> lf row, hand-aware)  64=FINAL(+bias,*vis->d_out)
// R16: BK=64 (128B rows -> 8 swizzle slots), single-buffered 32KB LDS,
// XOR-swizzle phys_slot = logical_slot ^ (row&7) applied on BOTH sides:
// gload SOURCE address pre-swizzled per-lane; fragment reads same XOR.
// Fixes the 8-way bank conflict of the old 64B-row layout (read critical path).
__global__ __launch_bounds__(256, 2) void gemm_bf16(
    const void* __restrict__ Av, const bf16* __restrict__ Bt,
    float* __restrict__ C32, bf16* __restrict__ Cout,
    const float* __restrict__ bias, const float* __restrict__ sc,
    const float* __restrict__ sh, int M, int N, int K, int lda, int flags)
{
  __shared__ __align__(16) bf16 As[128][64];
  __shared__ __align__(16) bf16 Bs[128][64];
  const int tid = threadIdx.x;
  const long m0 = (long)blockIdx.y * 128;
  const int n0 = blockIdx.x * 128;
  const int wave = tid >> 6, lane = tid & 63;
  const int wm = (wave & 1) * 64, wn = (wave >> 1) * 64;
  const int frow = lane & 15;
  const int lrow = lane >> 3;            // chunk row 0..7
  const int lslot = (lane & 7) ^ lrow;   // swizzled SOURCE slot
  const bf16* Ab = (const bf16*)Av;
  const float* Af = (const float*)Av;
  const int nk = K >> 6;
  const int lr = tid >> 1, lc = (tid & 1) * 32;   // f32-A staging map
  const int slotoff = ((lane >> 4) ^ (lane & 7)) << 4;  // kk=0 read offset
  f32x4 acc[4][4] = {};

  for (int kt = 0; kt < nk; kt++) {
    const int k0 = kt << 6;
    if (flags & 1) {   // f32 A: VALU convert-stage, swizzled direct write
      const float* ap = Af + (m0 + lr) * (long)lda + (k0 + lc);
      #pragma unroll
      for (int sq = 0; sq < 4; sq++) {
        bf16x8 t;
        #pragma unroll
        for (int u = 0; u < 8; u++) t[u] = (bf16)ap[sq * 8 + u];
        const int sl = (((lc >> 3) + sq) ^ (lr & 7));
        *(bf16x8*)((char*)&As[lr][0] + (sl << 4)) = t;
      }
    } else {           // async A: wave w stages 1KB chunks 4w..4w+3
      #pragma unroll
      for (int cc = 0; cc < 4; cc++) {
        const int ch = wave * 4 + cc;    // rows 8ch..8ch+7
        gload16(Ab + (m0 + ch * 8 + lrow) * (long)lda + (k0 + lslot * 8),
                &As[ch * 8][0]);
      }
    }
    #pragma unroll
    for (int cc = 0; cc < 4; cc++) {     // async B
      const int ch = wave * 4 + cc;
      gload16(Bt + ((long)(n0 + ch * 8 + lrow)) * K + (k0 + lslot * 8),
              &Bs[ch * 8][0]);
    }
    asm volatile("s_waitcnt vmcnt(0) lgkmcnt(0)" ::: "memory");
    __builtin_amdgcn_sched_barrier(0);
    __builtin_amdgcn_s_barrier();        // tile ready
    __builtin_amdgcn_sched_barrier(0);
    #pragma unroll
    for (int kk = 0; kk < 2; kk++) {
      const int so = slotoff ^ (kk << 6);  // logical slot += 4 -> bit2 of slot = bit6 of byte
      bf16x8 af[4], bg[4];
      #pragma unroll
      for (int i = 0; i < 4; i++)
        af[i] = *(const bf16x8*)((const char*)&As[wm + i * 16 + frow][0] + so);
      #pragma unroll
      for (int j = 0; j < 4; j++)
        bg[j] = *(const bf16x8*)((const char*)&Bs[wn + j * 16 + frow][0] + so);
      #pragma unroll
      for (int i = 0; i < 4; i++)
        #pragma unroll
        for (int j = 0; j < 4; j++)
          acc[i][j] = __builtin_amdgcn_mfma_f32_16x16x32_bf16(af[i], bg[j], acc[i][j], 0, 0, 0);
    }
    asm volatile("s_waitcnt lgkmcnt(0)" ::: "memory");
    __builtin_amdgcn_sched_barrier(0);
    __builtin_amdgcn_s_barrier();        // reads done (WAR guard for next stage)
    __builtin_amdgcn_sched_barrier(0);
  }
  const int col = lane & 15, rbase = (lane >> 4) * 4;
  #pragma unroll
  for (int i = 0; i < 4; i++) {
    #pragma unroll
    for (int j = 0; j < 4; j++) {
      const int nn = n0 + wn + j * 16 + col;
      #pragma unroll
      for (int r = 0; r < 4; r++) {
        const long mm = m0 + wm + i * 16 + rbase + r;
        if (mm >= M) continue;
        float v = acc[i][j][r];
        if (flags & 64) {            // FINAL: +o2b, *vis, f32 -> d_out[mm*63+nn]
          if (nn < 63) {
            float vv = (v + bias[nn]) * sc[(mm & (NBT - 1)) * 21 + nn / 3];
            C32[mm * 63 + nn] = vv;
          }
          continue;
        }
        if (flags & 2) { C32[mm * (long)N + nn] = v; continue; }
        if (flags & 8) v = v * sc[nn] + sh[nn];
        else if (bias) v += bias[nn];
        if (flags & 4) v = fmaxf(v, 0.f);
        if (flags & 16) {
          const int s = (int)(mm % SPAD);
          if (s == 0 || s == SPAD - 1) v = 0.f;
          Cout[mm * (long)N + nn] = (bf16)v;
        } else if (flags & 32) {
          const long hj = mm / SPAD; const int s = (int)(mm - hj * SPAD);
          if (s == 0 || s == SPAD - 1) continue;
          const int hand = (int)(hj / 168); const int lhj = (int)(hj - hand * 168);
          const int b = lhj / NJ; const int j2 = lhj - b * NJ;
          const long dst = (long)hand * NLF + ((long)b * 512 + (s - 1)) * NJ + j2;
          Cout[dst * (long)N + nn] = (bf16)v;
        } else {
          Cout[mm * (long)N + nn] = (bf16)v;
        }
      }
    }
  }
}

// ---------------- weight prep (f32 -> bf16) ----------------
__global__ void cvt_k(const float* __restrict__ s, bf16* __restrict__ d, long n) {
  long i = (long)blockIdx.x * 256 + threadIdx.x;
  if (i < n) d[i] = (bf16)s[i];
}
__global__ void prep_gatW(const float* __restrict__ W, bf16* __restrict__ Wt, int F) {
  long idx = (long)blockIdx.x * 256 + threadIdx.x;
  if (idx >= 256L * F) return;
  int n = (int)(idx / F), f = (int)(idx % F);
  Wt[idx] = (bf16)W[((long)(n >> 6) * F + f) * 64 + (n & 63)];
}
__global__ void prep_convw(const float* __restrict__ w, bf16* __restrict__ wp) {
  int idx = blockIdx.x * 256 + threadIdx.x;
  int n = idx / 768, k = idx % 768, tap = k >> 8, i = k & 255;
  wp[idx] = (bf16)w[(n * 256 + i) * 3 + tap];
}
__global__ void prep_out2(const float* __restrict__ w, bf16* __restrict__ wp) {
  int idx = blockIdx.x * 256 + threadIdx.x;
  wp[idx] = (idx < 63 * 256) ? (bf16)w[idx] : (bf16)0.f;
}
__global__ void prep_scsh(const float* __restrict__ cb, const float* __restrict__ g,
                          const float* __restrict__ be, const float* __restrict__ m,
                          const float* __restrict__ v, float* __restrict__ sc,
                          float* __restrict__ sh) {
  int c = threadIdx.x;
  float rs = rsqrtf(v[c] + 1e-5f) * g[c];
  sc[c] = rs; sh[c] = (cb[c] - m[c]) * rs + be[c];
}
__global__ void prep_bkv(const float* __restrict__ bk, const float* __restrict__ bv,
                         float* __restrict__ o) {
  int i = blockIdx.x * 256 + threadIdx.x;
  if (i >= 512) return;
  o[i] = (i < 256) ? bk[i] : bv[i - 256];
}
__global__ void pad_zero(bf16* __restrict__ convIn) {
  int idx = blockIdx.x * 256 + threadIdx.x;          // 336*2*256
  int hj = idx >> 9, s = ((idx >> 8) & 1) ? (SPAD - 1) : 0, c = idx & 255;
  convIn[((long)hj * SPAD + s) * DD + c] = (bf16)0.f;
}
__global__ void zero_out(float* __restrict__ o, long n) {
  long i = (long)blockIdx.x * 256 + threadIdx.x;
  if (i < n) o[i] = 0.f;
}

// ---------------- GAT attention (merged hands; in-place safe) ----------------
__global__ __launch_bounds__(256) void gat_attn(
    const bf16* __restrict__ Wh, const float* __restrict__ a,
    const float* __restrict__ adj, bf16* __restrict__ out, int convMode)
{
  const int bt = blockIdx.x, tid = threadIdx.x;
  __shared__ float whs[NJ][DD];
  __shared__ float s1[4][NJ], s2[4][NJ];
  __shared__ float att[4][NJ][NJ];
  const long base = (long)bt * NJ * DD;
  for (int i = tid; i < NJ * DD; i += 256)
    whs[i >> 8][i & 255] = (float)Wh[base + i];
  __syncthreads();
  if (tid < 4 * NJ) {
    const int h = tid / NJ, i = tid % NJ;
    float x1 = 0.f, x2 = 0.f;
    for (int d = 0; d < 64; d++) {
      const float w = whs[i][h * 64 + d];
      x1 += w * a[h * 128 + d];
      x2 += w * a[h * 128 + 64 + d];
    }
    s1[h][i] = x1; s2[h][i] = x2;
  }
  __syncthreads();
  for (int idx = tid; idx < 4 * NJ * NJ; idx += 256) {
    const int h = idx / (NJ * NJ), r = idx % (NJ * NJ), i = r / NJ, j = r % NJ;
    float e = s1[h][i] + s2[h][j];
    e = e > 0.f ? e : 0.2f * e;
    att[h][i][j] = (adj[i * NJ + j] > 0.f) ? e : -9e15f;
  }
  __syncthreads();
  if (tid < 4 * NJ) {
    const int h = tid / NJ, i = tid % NJ;
    float mx = -3e38f;
    for (int j = 0; j < NJ; j++) mx = fmaxf(mx, att[h][i][j]);
    float sum = 0.f;
    for (int j = 0; j < NJ; j++) { const float ex = __expf(att[h][i][j] - mx); att[h][i][j] = ex; sum += ex; }
    const float inv = 1.f / sum;
    for (int j = 0; j < NJ; j++) att[h][i][j] *= inv;
  }
  __syncthreads();
  const int hand = bt >> 12, b = (bt >> 9) & 7, t = bt & 511;
  for (int idx = tid; idx < NJ * DD; idx += 256) {
    const int i = idx >> 8, c = idx & 255, h = c >> 6;
    float s = 0.f;
    for (int j = 0; j < NJ; j++) s += att[h][i][j] * whs[j][c];
    s = s > 0.f ? s : (__expf(s) - 1.f);              // ELU
    const long row = convMode
        ? ((long)hand * CONVM1 + ((long)(b * NJ + i)) * SPAD + (t + 1))
        : ((long)bt * NJ + i);
    out[row * DD + c] = (bf16)s;
  }
}

// ---------------- MHA core (per bt block; O may alias Q; KV packed N=512) --
__global__ __launch_bounds__(256) void mha_core2(
    const bf16* __restrict__ Q, const bf16* __restrict__ KV,
    bf16* __restrict__ O)
{
  const int bt = blockIdx.x, tid = threadIdx.x;
  __shared__ bf16 qs[NJ][DD], ks[NJ][DD], vs[NJ][DD];
  __shared__ float att[4][NJ][NJ];
  const long baseq = (long)bt * NJ * DD;
  const long basekv = (long)bt * NJ * 512;
  for (int i = tid; i < NJ * DD; i += 256) {
    const int r = i >> 8, c = i & 255;
    qs[r][c] = Q[baseq + i];
    ks[r][c] = KV[basekv + r * 512 + c];
    vs[r][c] = KV[basekv + r * 512 + 256 + c];
  }
  __syncthreads();
  for (int idx = tid; idx < 4 * NJ * NJ; idx += 256) {
    const int h = idx / (NJ * NJ), r = idx % (NJ * NJ), i = r / NJ, j = r % NJ;
    float s = 0.f;
    for (int d = 0; d < 64; d++) s += (float)qs[i][h * 64 + d] * (float)ks[j][h * 64 + d];
    att[h][i][j] = s * 0.125f;
  }
  __syncthreads();
  if (tid < 4 * NJ) {
    const int h = tid / NJ, i = tid % NJ;
    float mx = -3e38f;
    for (int j = 0; j < NJ; j++) mx = fmaxf(mx, att[h][i][j]);
    float sum = 0.f;
    for (int j = 0; j < NJ; j++) { const float ex = __expf(att[h][i][j] - mx); att[h][i][j] = ex; sum += ex; }
    const float inv = 1.f / sum;
    for (int j = 0; j < NJ; j++) att[h][i][j] *= inv;
  }
  __syncthreads();
  for (int idx = tid; idx < NJ * DD; idx += 256) {
    const int i = idx >> 8, c = idx & 255, h = c >> 6;
    float s = 0.f;
    for (int j = 0; j < NJ; j++) s += att[h][i][j] * (float)vs[j][c];
    O[baseq + i * DD + c] = (bf16)s;
  }
}

// ---------------- residual + joint-mean pool (merged hands, grid 8192) -----
__global__ __launch_bounds__(256) void pool2_kernel(
    const bf16* __restrict__ lfBase, const bf16* __restrict__ ao,
    bf16* __restrict__ leBase)
{
  const int b = blockIdx.x, c = threadIdx.x;
  const int h = b >> 12, bt = b & (NBT - 1);
  const bf16* lfp = lfBase + ((long)(1 - h) * NLF + (long)bt * NJ) * DD;
  const bf16* aop = ao + ((long)b * NJ) * DD;
  float s = 0.f;
  for (int j = 0; j < NJ; j++)
    s += (float)lfp[j * DD + c] + 0.5f * (float)aop[j * DD + c];
  leBase[((long)(1 - h) * NBT + bt) * DD + c] = (bf16)(s * (1.f / 21.f));
}

// ---------------- persistent LSTM: weights in LDS (R15: 307us) -------------
#define REP16(X) X(0) X(1) X(2) X(3) X(4) X(5) X(6) X(7) X(8) X(9) X(10) X(11) \
  X(12) X(13) X(14) X(15)

#define LDS_FENCE() do { \
  asm volatile("s_waitcnt lgkmcnt(0)" ::: "memory"); \
  __builtin_amdgcn_sched_barrier(0); \
  __builtin_amdgcn_s_barrier(); \
  __builtin_amdgcn_sched_barrier(0); \
} while (0)

__global__ __launch_bounds__(512, 1) void lstm_lds(
    const float* __restrict__ xw,
    const float* __restrict__ whhF, const float* __restrict__ whhB,
    const float* __restrict__ bihF, const float* __restrict__ bhhF,
    const float* __restrict__ bihB, const float* __restrict__ bhhB,
    bf16* __restrict__ outL, bf16* __restrict__ outR)
{
  const int wg = blockIdx.x;
  const int hand = wg >> 4, dir = (wg >> 3) & 1, b = wg & 7;
  const int tid = threadIdx.x;
  const float* whh = dir ? whhB : whhF;

  __shared__ f16 whhs[512][136];   // 139,264 B -> 1 WG/CU
  __shared__ f16 hbuf[136];
  __shared__ float gsb[512];

  for (int i = tid; i < 512 * 128; i += 512)
    whhs[i >> 7][i & 127] = (f16)whh[i];
  if (tid < 136) hbuf[tid] = (f16)0.f;
  const float bias = (dir ? bihB : bihF)[tid] + (dir ? bhhB : bhhF)[tid];
  float c = 0.f;
  const float* xp = xw + ((long)hand * NBT + (long)b * 512) * 1024 + dir * 512;
  bf16* outp = hand ? outR : outL;
  const bool isG = (tid >> 7) == 2;
  float xv = xp[(long)(dir ? 511 : 0) * 1024 + tid];
  __syncthreads();

  const f16* wrow = &whhs[tid][0];
#define WRD(i) f16x8 w##i = *(const f16x8*)(wrow + (i) * 8);
  REP16(WRD)
#undef WRD

  for (int s = 0; s < 512; s++) {
    const int t = dir ? (511 - s) : s;
    const int tn = dir ? (510 - s) : (s + 1);
    float xnext = 0.f;
    if (s < 511) xnext = xp[(long)tn * 1024 + tid];
    float a0 = xv + bias, a1 = 0.f, a2 = 0.f, a3 = 0.f;
#define WDOT(i) { \
    const f16x8 hv = *(const f16x8*)(&hbuf[(i) * 8]); \
    a0 = __builtin_amdgcn_fdot2(__builtin_shufflevector(w##i, w##i, 0, 1), \
                                __builtin_shufflevector(hv, hv, 0, 1), a0, false); \
    a1 = __builtin_amdgcn_fdot2(__builtin_shufflevector(w##i, w##i, 2, 3), \
                                __builtin_shufflevector(hv, hv, 2, 3), a1, false); \
    a2 = __builtin_amdgcn_fdot2(__builtin_shufflevector(w##i, w##i, 4, 5), \
                                __builtin_shufflevector(hv, hv, 4, 5), a2, false); \
    a3 = __builtin_amdgcn_fdot2(__builtin_shufflevector(w##i, w##i, 6, 7), \
                                __builtin_shufflevector(hv, hv, 6, 7), a3, false); }
    REP16(WDOT)
#undef WDOT
    {   // phase A: per-gate transcendental by all 512 threads
      const float g = (a0 + a1) + (a2 + a3);
      gsb[tid] = isG ? (1.f - 2.f * __builtin_amdgcn_rcpf(1.f + __expf(2.f * g)))
                     : __builtin_amdgcn_rcpf(1.f + __expf(-g));
    }
    LDS_FENCE();
    if (tid < 128) {   // phase B: short combine chain
      const float si = gsb[tid],       sf = gsb[tid + 128];
      const float tg = gsb[tid + 256], so = gsb[tid + 384];
      c = sf * c + si * tg;
      const float tc = 1.f - 2.f * __builtin_amdgcn_rcpf(1.f + __expf(2.f * c));
      const float h = so * tc;
      hbuf[tid] = (f16)h;
      outp[((long)b * 512 + t) * 256 + dir * 128 + tid] = (bf16)h;
    }
    LDS_FENCE();
    xv = xnext;
  }
}

extern "C" void kernel_launch(void* const* d_in, const int* in_sizes, int n_in,
                              void* d_out, int out_size, void* d_ws, size_t ws_size,
                              hipStream_t stream) {
  (void)in_sizes; (void)n_in;
  const float* feats[2] = { (const float*)d_in[0], (const float*)d_in[1] };
  const float* adj  = (const float*)d_in[2];
  const float* vis  = (const float*)d_in[3];
  const float* gW[2] = { (const float*)d_in[4], (const float*)d_in[6] };
  const float* ga[2] = { (const float*)d_in[5], (const float*)d_in[7] };
  const float* cw_[2] = { (const float*)d_in[8],  (const float*)d_in[10] };
  const float* cb_[2] = { (const float*)d_in[9],  (const float*)d_in[11] };
  const float* bng[2] = { (const float*)d_in[12], (const float*)d_in[16] };
  const float* bnb[2] = { (const float*)d_in[13], (const float*)d_in[17] };
  const float* bnm[2] = { (const float*)d_in[14], (const float*)d_in[18] };
  const float* bnv[2] = { (const float*)d_in[15], (const float*)d_in[19] };
  const float* wq = (const float*)d_in[20], *wk = (const float*)d_in[21];
  const float* wv = (const float*)d_in[22], *wo = (const float*)d_in[23];
  const float* bq = (const float*)d_in[24], *bk = (const float*)d_in[25];
  const float* bv = (const float*)d_in[26], *bo = (const float*)d_in[27];
  const float* Lwih[2][2] = { { (const float*)d_in[28], (const float*)d_in[32] },
                              { (const float*)d_in[36], (const float*)d_in[40] } };
  const float* Lwhh[2][2] = { { (const float*)d_in[29], (const float*)d_in[33] },
                              { (const float*)d_in[37], (const float*)d_in[41] } };
  const float* Lbih[2][2] = { { (const float*)d_in[30], (const float*)d_in[34] },
                              { (const float*)d_in[38], (const float*)d_in[42] } };
  const float* Lbhh[2][2] = { { (const float*)d_in[31], (const float*)d_in[35] },
                              { (const float*)d_in[39], (const float*)d_in[43] } };
  const float* o1w = (const float*)d_in[44], *o1b = (const float*)d_in[45];
  const float* o2w = (const float*)d_in[46], *o2b = (const float*)d_in[47];

  char* base = (char*)d_ws;
  size_t off = 0;
  auto alloc = [&](size_t b) { size_t r = off; off += (b + 1023) & ~(size_t)1023; return r; };
  const size_t SZ_BIG = (size_t)CROWS_ALL * DD * 2;   // 88.6 MB
  const size_t SZ_BT  = (size_t)NBT * DD * 2;         // 2.10 MB
  const size_t o_w1t = alloc((size_t)256 * 512 * 2);
  const size_t o_w2t = alloc((size_t)256 * 256 * 2);
  const size_t o_cw1 = alloc((size_t)256 * 768 * 2);
  const size_t o_cw2 = alloc((size_t)256 * 768 * 2);
  const size_t o_wq  = alloc((size_t)256 * 256 * 2);
  const size_t o_wk  = alloc((size_t)256 * 256 * 2);   // wk|wv contiguous
  const size_t o_wv  = alloc((size_t)256 * 256 * 2);
  const size_t o_wo  = alloc((size_t)256 * 256 * 2);
  const size_t o_o1w = alloc((size_t)256 * 256 * 2);
  const size_t o_o2p = alloc((size_t)128 * 256 * 2);
  const size_t o_lw0 = alloc((size_t)512 * 256 * 2);   // lw0|lw1 contiguous
  const size_t o_lw1 = alloc((size_t)512 * 256 * 2);
  const size_t o_lw2 = alloc((size_t)512 * 256 * 2);   // lw2|lw3 contiguous
  const size_t o_lw3 = alloc((size_t)512 * 256 * 2);
  const size_t o_ss  = alloc((size_t)4 * 256 * 4);
  const size_t o_bkv = alloc((size_t)512 * 4);
  const size_t o_BA  = alloc(SZ_BIG);
  const size_t o_BH  = alloc(SZ_BIG);
  const size_t o_lfL = alloc((size_t)NLF * DD * 2);   // lfL|lfR contiguous
  const size_t o_lfR = alloc((size_t)NLF * DD * 2);
  const size_t o_le  = alloc(SZ_BT);   // le|re contiguous
  const size_t o_re  = alloc(SZ_BT);
  const size_t o_h1L = alloc(SZ_BT);   // h1L|h1R contiguous
  const size_t o_h1R = alloc(SZ_BT);
  const size_t o_hoL = alloc(SZ_BT);   // hoL|hoR contiguous
  const size_t o_hoR = alloc(SZ_BT);
  const size_t NEED = off;
  if (ws_size < NEED) {
    zero_out<<<(out_size + 255) / 256, 256, 0, stream>>>((float*)d_out, out_size);
    return;
  }
  auto P = [&](size_t o_) { return (void*)(base + o_); };

  auto gemm = [&](const void* A, const void* Bt, void* c32, void* co,
                  const void* bias_, const void* sc_, const void* sh_,
                  long M, int N, int K, int lda, int flags) {
    dim3 g((unsigned)(N / 128), (unsigned)((M + 127) / 128));
    gemm_bf16<<<g, 256, 0, stream>>>(A, (const bf16*)Bt, (float*)c32, (bf16*)co,
                                     (const float*)bias_, (const float*)sc_,
                                     (const float*)sh_, (int)M, N, K, lda, flags);
  };
  auto cvt = [&](const float* s, void* d, long n) {
    cvt_k<<<(unsigned)((n + 255) / 256), 256, 0, stream>>>(s, (bf16*)d, n);
  };

  // ---- weight prep ----
  prep_gatW<<<512, 256, 0, stream>>>(gW[0], (bf16*)P(o_w1t), 512);
  prep_gatW<<<256, 256, 0, stream>>>(gW[1], (bf16*)P(o_w2t), 256);
  prep_convw<<<768, 256, 0, stream>>>(cw_[0], (bf16*)P(o_cw1));
  prep_convw<<<768, 256, 0, stream>>>(cw_[1], (bf16*)P(o_cw2));
  cvt(wq, P(o_wq), 65536); cvt(wk, P(o_wk), 65536);
  cvt(wv, P(o_wv), 65536); cvt(wo, P(o_wo), 65536);
  cvt(o1w, P(o_o1w), 65536);
  cvt(Lwih[0][0], P(o_lw0), 131072); cvt(Lwih[0][1], P(o_lw1), 131072);
  cvt(Lwih[1][0], P(o_lw2), 131072); cvt(Lwih[1][1], P(o_lw3), 131072);
  prep_out2<<<128, 256, 0, stream>>>(o2w, (bf16*)P(o_o2p));
  float* sc1 = (float*)P(o_ss); float* sh1 = sc1 + 256;
  float* sc2 = sh1 + 256;       float* sh2 = sc2 + 256;
  prep_scsh<<<1, 256, 0, stream>>>(cb_[0], bng[0], bnb[0], bnm[0], bnv[0], sc1, sh1);
  prep_scsh<<<1, 256, 0, stream>>>(cb_[1], bng[1], bnb[1], bnm[1], bnv[1], sc2, sh2);
  prep_bkv<<<2, 256, 0, stream>>>(bk, bv, (float*)P(o_bkv));

  bf16* BA = (bf16*)P(o_BA);
  bf16* BH = (bf16*)P(o_BH);
  bf16* lfb[2] = { (bf16*)P(o_lfL), (bf16*)P(o_lfR) };

  // ---- merged front ----
  for (int hd = 0; hd < 2; hd++)
    gemm(feats[hd], P(o_w1t), nullptr, BA + (size_t)hd * NLF * DD,
         nullptr, nullptr, nullptr, NLF, 256, 512, 512, 1);      // A_F32
  gat_attn<<<2 * NBT, 256, 0, stream>>>(BA, ga[0], adj, BA, 0);
  gemm(BA, P(o_w2t), nullptr, BH, nullptr, nullptr, nullptr,
       2 * NLF, 256, 256, 256, 0);
  pad_zero<<<672, 256, 0, stream>>>(BA + DD);
  gat_attn<<<2 * NBT, 256, 0, stream>>>(BH, ga[1], adj, BA + DD, 1);
  gemm(BA, P(o_cw1), nullptr, BH + DD, nullptr, sc1, sh1,
       CONVM2, 256, 768, 256, 8 | 4 | 16);
  gemm(BH, P(o_cw2), nullptr, lfb[0], nullptr, sc2, sh2,
       CONVM2, 256, 768, 256, 8 | 4 | 32);

  // ---- cross-hand MHA (Q merged, KV per-pass, WO+pool merged) ----
  gemm(lfb[0], P(o_wq), nullptr, BA, bq, nullptr, nullptr, 2 * NLF, 256, 256, 256, 0);
  gemm(lfb[1], P(o_wk), nullptr, BH, P(o_bkv), nullptr, nullptr, NLF, 512, 256, 256, 0);
  mha_core2<<<NBT, 256, 0, stream>>>(BA, BH, BA);
  gemm(lfb[0], P(o_wk), nullptr, BH, P(o_bkv), nullptr, nullptr, NLF, 512, 256, 256, 0);
  mha_core2<<<NBT, 256, 0, stream>>>(BA + (size_t)NLF * DD, BH, BA + (size_t)NLF * DD);
  gemm(BA, P(o_wo), nullptr, BH, bo, nullptr, nullptr, 2 * NLF, 256, 256, 256, 0);
  pool2_kernel<<<2 * NBT, 256, 0, stream>>>(lfb[0], BH, (bf16*)P(o_le));

  // ---- BiLSTM ----
  float* xw = (float*)P(o_BH);
  gemm(P(o_le), P(o_lw0), xw, nullptr, nullptr, nullptr, nullptr,
       2 * NBT, 1024, 256, 256, 2);
  lstm_lds<<<32, 512, 0, stream>>>(xw, Lwhh[0][0], Lwhh[0][1],
      Lbih[0][0], Lbhh[0][0], Lbih[0][1], Lbhh[0][1],
      (bf16*)P(o_h1L), (bf16*)P(o_h1R));
  gemm(P(o_h1L), P(o_lw2), xw, nullptr, nullptr, nullptr, nullptr,
       2 * NBT, 1024, 256, 256, 2);
  lstm_lds<<<32, 512, 0, stream>>>(xw, Lwhh[1][0], Lwhh[1][1],
      Lbih[1][0], Lbhh[1][0], Lbih[1][1], Lbhh[1][1],
      (bf16*)P(o_hoL), (bf16*)P(o_hoR));

  // ---- heads ----
  gemm(P(o_hoL), P(o_o1w), nullptr, BA, o1b, nullptr, nullptr,
       2 * NBT, 256, 256, 256, 4);
  gemm(BA, P(o_o2p), d_out, nullptr, o2b, vis, nullptr,
       2 * NBT, 128, 256, 256, 64);
}

// Round 17
// 2110.090 us; speedup vs baseline: 1.0363x; 1.0363x over previous
//
#include <hip/hip_runtime.h>

typedef __bf16 bf16;
typedef bf16 bf16x8 __attribute__((ext_vector_type(8)));
typedef float f32x4 __attribute__((ext_vector_type(4)));
typedef _Float16 f16;
typedef f16 f16x8 __attribute__((ext_vector_type(8)));

#define NBT 4096      // B*T = 8*512
#define NJ 21
#define NLF 86016     // NBT*NJ (one hand)
#define DD 256
#define CONVM1 86352  // 168*514 (one hand)
#define CONVM2 172704 // both hands
#define SPAD 514
#define CROWS_ALL 173056  // 1 guard + 172704 + slack

// async global->LDS, 16B per lane; LDS dest is WAVE-UNIFORM base + lane*16
__device__ __forceinline__ void gload16(const bf16* g, bf16* l) {
  __builtin_amdgcn_global_load_lds(
      (const __attribute__((address_space(1))) unsigned int*)g,
      (__attribute__((address_space(3))) unsigned int*)l, 16, 0, 0);
}

// flags: 1=A_F32  2=OUT_F32(C32)  4=RELU  8=BNSS(sc/sh)  16=PADZ(conv layout)
//        32=LFOUT(conv row -> lf row, hand-aware)  64=FINAL(+bias,*vis->d_out)
// R17: reverted to the R15 GEMM (BK=32, double-buffered, counted vmcnt(4)) —
// R16's bundled BK=64/single-buffer/swizzle change regressed +77us.
__global__ __launch_bounds__(256, 2) void gemm_bf16(
    const void* __restrict__ Av, const bf16* __restrict__ Bt,
    float* __restrict__ C32, bf16* __restrict__ Cout,
    const float* __restrict__ bias, const float* __restrict__ sc,
    const float* __restrict__ sh, int M, int N, int K, int lda, int flags)
{
  __shared__ __align__(16) bf16 As[2][128][32];
  __shared__ __align__(16) bf16 Bs[2][128][32];
  const int tid = threadIdx.x;
  const long m0 = (long)blockIdx.y * 128;
  const int n0 = blockIdx.x * 128;
  const int wave = tid >> 6, lane = tid & 63;
  const int wm = (wave & 1) * 64, wn = (wave >> 1) * 64;
  const int frow = lane & 15, fkb = (lane >> 4) * 8;
  const int crow = lane >> 2, ccol = (lane & 3) * 8;
  const bf16* Ab = (const bf16*)Av;
  const float* Af = (const float*)Av;
  const int nk = K >> 5;
  const int ch0 = wave * 2, ch1 = ch0 + 1;
  const long arow0 = (m0 + ch0 * 16 + crow) * (long)lda + ccol;
  const long arow1 = (m0 + ch1 * 16 + crow) * (long)lda + ccol;
  const long brow0 = ((long)(n0 + ch0 * 16 + crow)) * K + ccol;
  const long brow1 = ((long)(n0 + ch1 * 16 + crow)) * K + ccol;
  const int lr = tid >> 1, lc = (tid & 1) * 16;   // f32-A staging map

  auto stageA_f32 = [&](int buf, int k0) {
    const float* ap = Af + (m0 + lr) * (long)lda + (k0 + lc);
    bf16x8 t0, t1;
    #pragma unroll
    for (int u = 0; u < 8; u++) { t0[u] = (bf16)ap[u]; t1[u] = (bf16)ap[8 + u]; }
    *(bf16x8*)(&As[buf][lr][lc])     = t0;
    *(bf16x8*)(&As[buf][lr][lc + 8]) = t1;
  };

  f32x4 acc[4][4] = {};
  if (flags & 1) stageA_f32(0, 0);
  else {
    gload16(Ab + arow0, &As[0][ch0 * 16][0]);
    gload16(Ab + arow1, &As[0][ch1 * 16][0]);
  }
  gload16(Bt + brow0, &Bs[0][ch0 * 16][0]);
  gload16(Bt + brow1, &Bs[0][ch1 * 16][0]);

  for (int kt = 0; kt < nk; kt++) {
    const int cur = kt & 1;
    if (kt + 1 < nk) {
      const int k0 = (kt + 1) << 5;
      if (flags & 1) {
        stageA_f32(cur ^ 1, k0);
        gload16(Bt + brow0 + k0, &Bs[cur ^ 1][ch0 * 16][0]);
        gload16(Bt + brow1 + k0, &Bs[cur ^ 1][ch1 * 16][0]);
        asm volatile("s_waitcnt vmcnt(2) lgkmcnt(0)" ::: "memory");
      } else {
        gload16(Ab + arow0 + k0, &As[cur ^ 1][ch0 * 16][0]);
        gload16(Ab + arow1 + k0, &As[cur ^ 1][ch1 * 16][0]);
        gload16(Bt + brow0 + k0, &Bs[cur ^ 1][ch0 * 16][0]);
        gload16(Bt + brow1 + k0, &Bs[cur ^ 1][ch1 * 16][0]);
        asm volatile("s_waitcnt vmcnt(4) lgkmcnt(0)" ::: "memory");
      }
    } else {
      asm volatile("s_waitcnt vmcnt(0) lgkmcnt(0)" ::: "memory");
    }
    __builtin_amdgcn_sched_barrier(0);
    __builtin_amdgcn_s_barrier();
    __builtin_amdgcn_sched_barrier(0);
    bf16x8 af[4], bg[4];
    #pragma unroll
    for (int i = 0; i < 4; i++) af[i] = *(const bf16x8*)(&As[cur][wm + i * 16 + frow][fkb]);
    #pragma unroll
    for (int j = 0; j < 4; j++) bg[j] = *(const bf16x8*)(&Bs[cur][wn + j * 16 + frow][fkb]);
    #pragma unroll
    for (int i = 0; i < 4; i++)
      #pragma unroll
      for (int j = 0; j < 4; j++)
        acc[i][j] = __builtin_amdgcn_mfma_f32_16x16x32_bf16(af[i], bg[j], acc[i][j], 0, 0, 0);
    asm volatile("s_waitcnt lgkmcnt(0)" ::: "memory");
    __builtin_amdgcn_sched_barrier(0);
    __builtin_amdgcn_s_barrier();
    __builtin_amdgcn_sched_barrier(0);
  }
  const int col = lane & 15, rbase = (lane >> 4) * 4;
  #pragma unroll
  for (int i = 0; i < 4; i++) {
    #pragma unroll
    for (int j = 0; j < 4; j++) {
      const int nn = n0 + wn + j * 16 + col;
      #pragma unroll
      for (int r = 0; r < 4; r++) {
        const long mm = m0 + wm + i * 16 + rbase + r;
        if (mm >= M) continue;
        float v = acc[i][j][r];
        if (flags & 64) {            // FINAL: +o2b, *vis, f32 -> d_out[mm*63+nn]
          if (nn < 63) {
            float vv = (v + bias[nn]) * sc[(mm & (NBT - 1)) * 21 + nn / 3];
            C32[mm * 63 + nn] = vv;
          }
          continue;
        }
        if (flags & 2) { C32[mm * (long)N + nn] = v; continue; }
        if (flags & 8) v = v * sc[nn] + sh[nn];
        else if (bias) v += bias[nn];
        if (flags & 4) v = fmaxf(v, 0.f);
        if (flags & 16) {
          const int s = (int)(mm % SPAD);
          if (s == 0 || s == SPAD - 1) v = 0.f;
          Cout[mm * (long)N + nn] = (bf16)v;
        } else if (flags & 32) {
          const long hj = mm / SPAD; const int s = (int)(mm - hj * SPAD);
          if (s == 0 || s == SPAD - 1) continue;
          const int hand = (int)(hj / 168); const int lhj = (int)(hj - hand * 168);
          const int b = lhj / NJ; const int j2 = lhj - b * NJ;
          const long dst = (long)hand * NLF + ((long)b * 512 + (s - 1)) * NJ + j2;
          Cout[dst * (long)N + nn] = (bf16)v;
        } else {
          Cout[mm * (long)N + nn] = (bf16)v;
        }
      }
    }
  }
}

// ---------------- weight prep (f32 -> bf16) ----------------
__global__ void cvt_k(const float* __restrict__ s, bf16* __restrict__ d, long n) {
  long i = (long)blockIdx.x * 256 + threadIdx.x;
  if (i < n) d[i] = (bf16)s[i];
}
__global__ void prep_gatW(const float* __restrict__ W, bf16* __restrict__ Wt, int F) {
  long idx = (long)blockIdx.x * 256 + threadIdx.x;
  if (idx >= 256L * F) return;
  int n = (int)(idx / F), f = (int)(idx % F);
  Wt[idx] = (bf16)W[((long)(n >> 6) * F + f) * 64 + (n & 63)];
}
__global__ void prep_convw(const float* __restrict__ w, bf16* __restrict__ wp) {
  int idx = blockIdx.x * 256 + threadIdx.x;
  int n = idx / 768, k = idx % 768, tap = k >> 8, i = k & 255;
  wp[idx] = (bf16)w[(n * 256 + i) * 3 + tap];
}
__global__ void prep_out2(const float* __restrict__ w, bf16* __restrict__ wp) {
  int idx = blockIdx.x * 256 + threadIdx.x;
  wp[idx] = (idx < 63 * 256) ? (bf16)w[idx] : (bf16)0.f;
}
__global__ void prep_scsh(const float* __restrict__ cb, const float* __restrict__ g,
                          const float* __restrict__ be, const float* __restrict__ m,
                          const float* __restrict__ v, float* __restrict__ sc,
                          float* __restrict__ sh) {
  int c = threadIdx.x;
  float rs = rsqrtf(v[c] + 1e-5f) * g[c];
  sc[c] = rs; sh[c] = (cb[c] - m[c]) * rs + be[c];
}
__global__ void prep_bkv(const float* __restrict__ bk, const float* __restrict__ bv,
                         float* __restrict__ o) {
  int i = blockIdx.x * 256 + threadIdx.x;
  if (i >= 512) return;
  o[i] = (i < 256) ? bk[i] : bv[i - 256];
}
__global__ void pad_zero(bf16* __restrict__ convIn) {
  int idx = blockIdx.x * 256 + threadIdx.x;          // 336*2*256
  int hj = idx >> 9, s = ((idx >> 8) & 1) ? (SPAD - 1) : 0, c = idx & 255;
  convIn[((long)hj * SPAD + s) * DD + c] = (bf16)0.f;
}
__global__ void zero_out(float* __restrict__ o, long n) {
  long i = (long)blockIdx.x * 256 + threadIdx.x;
  if (i < n) o[i] = 0.f;
}

// ---------------- GAT attention (merged hands; in-place safe) ----------------
__global__ __launch_bounds__(256) void gat_attn(
    const bf16* __restrict__ Wh, const float* __restrict__ a,
    const float* __restrict__ adj, bf16* __restrict__ out, int convMode)
{
  const int bt = blockIdx.x, tid = threadIdx.x;
  __shared__ float whs[NJ][DD];
  __shared__ float s1[4][NJ], s2[4][NJ];
  __shared__ float att[4][NJ][NJ];
  const long base = (long)bt * NJ * DD;
  for (int i = tid; i < NJ * DD; i += 256)
    whs[i >> 8][i & 255] = (float)Wh[base + i];
  __syncthreads();
  if (tid < 4 * NJ) {
    const int h = tid / NJ, i = tid % NJ;
    float x1 = 0.f, x2 = 0.f;
    for (int d = 0; d < 64; d++) {
      const float w = whs[i][h * 64 + d];
      x1 += w * a[h * 128 + d];
      x2 += w * a[h * 128 + 64 + d];
    }
    s1[h][i] = x1; s2[h][i] = x2;
  }
  __syncthreads();
  for (int idx = tid; idx < 4 * NJ * NJ; idx += 256) {
    const int h = idx / (NJ * NJ), r = idx % (NJ * NJ), i = r / NJ, j = r % NJ;
    float e = s1[h][i] + s2[h][j];
    e = e > 0.f ? e : 0.2f * e;
    att[h][i][j] = (adj[i * NJ + j] > 0.f) ? e : -9e15f;
  }
  __syncthreads();
  if (tid < 4 * NJ) {
    const int h = tid / NJ, i = tid % NJ;
    float mx = -3e38f;
    for (int j = 0; j < NJ; j++) mx = fmaxf(mx, att[h][i][j]);
    float sum = 0.f;
    for (int j = 0; j < NJ; j++) { const float ex = __expf(att[h][i][j] - mx); att[h][i][j] = ex; sum += ex; }
    const float inv = 1.f / sum;
    for (int j = 0; j < NJ; j++) att[h][i][j] *= inv;
  }
  __syncthreads();
  const int hand = bt >> 12, b = (bt >> 9) & 7, t = bt & 511;
  for (int idx = tid; idx < NJ * DD; idx += 256) {
    const int i = idx >> 8, c = idx & 255, h = c >> 6;
    float s = 0.f;
    for (int j = 0; j < NJ; j++) s += att[h][i][j] * whs[j][c];
    s = s > 0.f ? s : (__expf(s) - 1.f);              // ELU
    const long row = convMode
        ? ((long)hand * CONVM1 + ((long)(b * NJ + i)) * SPAD + (t + 1))
        : ((long)bt * NJ + i);
    out[row * DD + c] = (bf16)s;
  }
}

// ---------------- MHA core (per bt block; O may alias Q; KV packed N=512) --
__global__ __launch_bounds__(256) void mha_core2(
    const bf16* __restrict__ Q, const bf16* __restrict__ KV,
    bf16* __restrict__ O)
{
  const int bt = blockIdx.x, tid = threadIdx.x;
  __shared__ bf16 qs[NJ][DD], ks[NJ][DD], vs[NJ][DD];
  __shared__ float att[4][NJ][NJ];
  const long baseq = (long)bt * NJ * DD;
  const long basekv = (long)bt * NJ * 512;
  for (int i = tid; i < NJ * DD; i += 256) {
    const int r = i >> 8, c = i & 255;
    qs[r][c] = Q[baseq + i];
    ks[r][c] = KV[basekv + r * 512 + c];
    vs[r][c] = KV[basekv + r * 512 + 256 + c];
  }
  __syncthreads();
  for (int idx = tid; idx < 4 * NJ * NJ; idx += 256) {
    const int h = idx / (NJ * NJ), r = idx % (NJ * NJ), i = r / NJ, j = r % NJ;
    float s = 0.f;
    for (int d = 0; d < 64; d++) s += (float)qs[i][h * 64 + d] * (float)ks[j][h * 64 + d];
    att[h][i][j] = s * 0.125f;
  }
  __syncthreads();
  if (tid < 4 * NJ) {
    const int h = tid / NJ, i = tid % NJ;
    float mx = -3e38f;
    for (int j = 0; j < NJ; j++) mx = fmaxf(mx, att[h][i][j]);
    float sum = 0.f;
    for (int j = 0; j < NJ; j++) { const float ex = __expf(att[h][i][j] - mx); att[h][i][j] = ex; sum += ex; }
    const float inv = 1.f / sum;
    for (int j = 0; j < NJ; j++) att[h][i][j] *= inv;
  }
  __syncthreads();
  for (int idx = tid; idx < NJ * DD; idx += 256) {
    const int i = idx >> 8, c = idx & 255, h = c >> 6;
    float s = 0.f;
    for (int j = 0; j < NJ; j++) s += att[h][i][j] * (float)vs[j][c];
    O[baseq + i * DD + c] = (bf16)s;
  }
}

// ---------------- residual + joint-mean pool (merged hands, grid 8192) -----
__global__ __launch_bounds__(256) void pool2_kernel(
    const bf16* __restrict__ lfBase, const bf16* __restrict__ ao,
    bf16* __restrict__ leBase)
{
  const int b = blockIdx.x, c = threadIdx.x;
  const int h = b >> 12, bt = b & (NBT - 1);
  const bf16* lfp = lfBase + ((long)(1 - h) * NLF + (long)bt * NJ) * DD;
  const bf16* aop = ao + ((long)b * NJ) * DD;
  float s = 0.f;
  for (int j = 0; j < NJ; j++)
    s += (float)lfp[j * DD + c] + 0.5f * (float)aop[j * DD + c];
  leBase[((long)(1 - h) * NBT + bt) * DD + c] = (bf16)(s * (1.f / 21.f));
}

// ---------------- persistent LSTM: weights in LDS (R15: 307us) -------------
#define REP16(X) X(0) X(1) X(2) X(3) X(4) X(5) X(6) X(7) X(8) X(9) X(10) X(11) \
  X(12) X(13) X(14) X(15)

#define LDS_FENCE() do { \
  asm volatile("s_waitcnt lgkmcnt(0)" ::: "memory"); \
  __builtin_amdgcn_sched_barrier(0); \
  __builtin_amdgcn_s_barrier(); \
  __builtin_amdgcn_sched_barrier(0); \
} while (0)

__global__ __launch_bounds__(512, 1) void lstm_lds(
    const float* __restrict__ xw,
    const float* __restrict__ whhF, const float* __restrict__ whhB,
    const float* __restrict__ bihF, const float* __restrict__ bhhF,
    const float* __restrict__ bihB, const float* __restrict__ bhhB,
    bf16* __restrict__ outL, bf16* __restrict__ outR)
{
  const int wg = blockIdx.x;
  const int hand = wg >> 4, dir = (wg >> 3) & 1, b = wg & 7;
  const int tid = threadIdx.x;
  const float* whh = dir ? whhB : whhF;

  __shared__ f16 whhs[512][136];   // 139,264 B -> 1 WG/CU
  __shared__ f16 hbuf[136];
  __shared__ float gsb[512];

  for (int i = tid; i < 512 * 128; i += 512)
    whhs[i >> 7][i & 127] = (f16)whh[i];
  if (tid < 136) hbuf[tid] = (f16)0.f;
  const float bias = (dir ? bihB : bihF)[tid] + (dir ? bhhB : bhhF)[tid];
  float c = 0.f;
  const float* xp = xw + ((long)hand * NBT + (long)b * 512) * 1024 + dir * 512;
  bf16* outp = hand ? outR : outL;
  const bool isG = (tid >> 7) == 2;
  float xv = xp[(long)(dir ? 511 : 0) * 1024 + tid];
  __syncthreads();

  const f16* wrow = &whhs[tid][0];
#define WRD(i) f16x8 w##i = *(const f16x8*)(wrow + (i) * 8);
  REP16(WRD)
#undef WRD

  for (int s = 0; s < 512; s++) {
    const int t = dir ? (511 - s) : s;
    const int tn = dir ? (510 - s) : (s + 1);
    float xnext = 0.f;
    if (s < 511) xnext = xp[(long)tn * 1024 + tid];
    float a0 = xv + bias, a1 = 0.f, a2 = 0.f, a3 = 0.f;
#define WDOT(i) { \
    const f16x8 hv = *(const f16x8*)(&hbuf[(i) * 8]); \
    a0 = __builtin_amdgcn_fdot2(__builtin_shufflevector(w##i, w##i, 0, 1), \
                                __builtin_shufflevector(hv, hv, 0, 1), a0, false); \
    a1 = __builtin_amdgcn_fdot2(__builtin_shufflevector(w##i, w##i, 2, 3), \
                                __builtin_shufflevector(hv, hv, 2, 3), a1, false); \
    a2 = __builtin_amdgcn_fdot2(__builtin_shufflevector(w##i, w##i, 4, 5), \
                                __builtin_shufflevector(hv, hv, 4, 5), a2, false); \
    a3 = __builtin_amdgcn_fdot2(__builtin_shufflevector(w##i, w##i, 6, 7), \
                                __builtin_shufflevector(hv, hv, 6, 7), a3, false); }
    REP16(WDOT)
#undef WDOT
    {   // phase A: per-gate transcendental by all 512 threads
      const float g = (a0 + a1) + (a2 + a3);
      gsb[tid] = isG ? (1.f - 2.f * __builtin_amdgcn_rcpf(1.f + __expf(2.f * g)))
                     : __builtin_amdgcn_rcpf(1.f + __expf(-g));
    }
    LDS_FENCE();
    if (tid < 128) {   // phase B: short combine chain
      const float si = gsb[tid],       sf = gsb[tid + 128];
      const float tg = gsb[tid + 256], so = gsb[tid + 384];
      c = sf * c + si * tg;
      const float tc = 1.f - 2.f * __builtin_amdgcn_rcpf(1.f + __expf(2.f * c));
      const float h = so * tc;
      hbuf[tid] = (f16)h;
      outp[((long)b * 512 + t) * 256 + dir * 128 + tid] = (bf16)h;
    }
    LDS_FENCE();
    xv = xnext;
  }
}

extern "C" void kernel_launch(void* const* d_in, const int* in_sizes, int n_in,
                              void* d_out, int out_size, void* d_ws, size_t ws_size,
                              hipStream_t stream) {
  (void)in_sizes; (void)n_in;
  const float* feats[2] = { (const float*)d_in[0], (const float*)d_in[1] };
  const float* adj  = (const float*)d_in[2];
  const float* vis  = (const float*)d_in[3];
  const float* gW[2] = { (const float*)d_in[4], (const float*)d_in[6] };
  const float* ga[2] = { (const float*)d_in[5], (const float*)d_in[7] };
  const float* cw_[2] = { (const float*)d_in[8],  (const float*)d_in[10] };
  const float* cb_[2] = { (const float*)d_in[9],  (const float*)d_in[11] };
  const float* bng[2] = { (const float*)d_in[12], (const float*)d_in[16] };
  const float* bnb[2] = { (const float*)d_in[13], (const float*)d_in[17] };
  const float* bnm[2] = { (const float*)d_in[14], (const float*)d_in[18] };
  const float* bnv[2] = { (const float*)d_in[15], (const float*)d_in[19] };
  const float* wq = (const float*)d_in[20], *wk = (const float*)d_in[21];
  const float* wv = (const float*)d_in[22], *wo = (const float*)d_in[23];
  const float* bq = (const float*)d_in[24], *bk = (const float*)d_in[25];
  const float* bv = (const float*)d_in[26], *bo = (const float*)d_in[27];
  const float* Lwih[2][2] = { { (const float*)d_in[28], (const float*)d_in[32] },
                              { (const float*)d_in[36], (const float*)d_in[40] } };
  const float* Lwhh[2][2] = { { (const float*)d_in[29], (const float*)d_in[33] },
                              { (const float*)d_in[37], (const float*)d_in[41] } };
  const float* Lbih[2][2] = { { (const float*)d_in[30], (const float*)d_in[34] },
                              { (const float*)d_in[38], (const float*)d_in[42] } };
  const float* Lbhh[2][2] = { { (const float*)d_in[31], (const float*)d_in[35] },
                              { (const float*)d_in[39], (const float*)d_in[43] } };
  const float* o1w = (const float*)d_in[44], *o1b = (const float*)d_in[45];
  const float* o2w = (const float*)d_in[46], *o2b = (const float*)d_in[47];

  char* base = (char*)d_ws;
  size_t off = 0;
  auto alloc = [&](size_t b) { size_t r = off; off += (b + 1023) & ~(size_t)1023; return r; };
  const size_t SZ_BIG = (size_t)CROWS_ALL * DD * 2;   // 88.6 MB
  const size_t SZ_BT  = (size_t)NBT * DD * 2;         // 2.10 MB
  const size_t o_w1t = alloc((size_t)256 * 512 * 2);
  const size_t o_w2t = alloc((size_t)256 * 256 * 2);
  const size_t o_cw1 = alloc((size_t)256 * 768 * 2);
  const size_t o_cw2 = alloc((size_t)256 * 768 * 2);
  const size_t o_wq  = alloc((size_t)256 * 256 * 2);
  const size_t o_wk  = alloc((size_t)256 * 256 * 2);   // wk|wv contiguous
  const size_t o_wv  = alloc((size_t)256 * 256 * 2);
  const size_t o_wo  = alloc((size_t)256 * 256 * 2);
  const size_t o_o1w = alloc((size_t)256 * 256 * 2);
  const size_t o_o2p = alloc((size_t)128 * 256 * 2);
  const size_t o_lw0 = alloc((size_t)512 * 256 * 2);   // lw0|lw1 contiguous
  const size_t o_lw1 = alloc((size_t)512 * 256 * 2);
  const size_t o_lw2 = alloc((size_t)512 * 256 * 2);   // lw2|lw3 contiguous
  const size_t o_lw3 = alloc((size_t)512 * 256 * 2);
  const size_t o_ss  = alloc((size_t)4 * 256 * 4);
  const size_t o_bkv = alloc((size_t)512 * 4);
  const size_t o_BA  = alloc(SZ_BIG);
  const size_t o_BH  = alloc(SZ_BIG);
  const size_t o_lfL = alloc((size_t)NLF * DD * 2);   // lfL|lfR contiguous
  const size_t o_lfR = alloc((size_t)NLF * DD * 2);
  const size_t o_le  = alloc(SZ_BT);   // le|re contiguous
  const size_t o_re  = alloc(SZ_BT);
  const size_t o_h1L = alloc(SZ_BT);   // h1L|h1R contiguous
  const size_t o_h1R = alloc(SZ_BT);
  const size_t o_hoL = alloc(SZ_BT);   // hoL|hoR contiguous
  const size_t o_hoR = alloc(SZ_BT);
  const size_t NEED = off;
  if (ws_size < NEED) {
    zero_out<<<(out_size + 255) / 256, 256, 0, stream>>>((float*)d_out, out_size);
    return;
  }
  auto P = [&](size_t o_) { return (void*)(base + o_); };

  auto gemm = [&](const void* A, const void* Bt, void* c32, void* co,
                  const void* bias_, const void* sc_, const void* sh_,
                  long M, int N, int K, int lda, int flags) {
    dim3 g((unsigned)(N / 128), (unsigned)((M + 127) / 128));
    gemm_bf16<<<g, 256, 0, stream>>>(A, (const bf16*)Bt, (float*)c32, (bf16*)co,
                                     (const float*)bias_, (const float*)sc_,
                                     (const float*)sh_, (int)M, N, K, lda, flags);
  };
  auto cvt = [&](const float* s, void* d, long n) {
    cvt_k<<<(unsigned)((n + 255) / 256), 256, 0, stream>>>(s, (bf16*)d, n);
  };

  // ---- weight prep ----
  prep_gatW<<<512, 256, 0, stream>>>(gW[0], (bf16*)P(o_w1t), 512);
  prep_gatW<<<256, 256, 0, stream>>>(gW[1], (bf16*)P(o_w2t), 256);
  prep_convw<<<768, 256, 0, stream>>>(cw_[0], (bf16*)P(o_cw1));
  prep_convw<<<768, 256, 0, stream>>>(cw_[1], (bf16*)P(o_cw2));
  cvt(wq, P(o_wq), 65536); cvt(wk, P(o_wk), 65536);
  cvt(wv, P(o_wv), 65536); cvt(wo, P(o_wo), 65536);
  cvt(o1w, P(o_o1w), 65536);
  cvt(Lwih[0][0], P(o_lw0), 131072); cvt(Lwih[0][1], P(o_lw1), 131072);
  cvt(Lwih[1][0], P(o_lw2), 131072); cvt(Lwih[1][1], P(o_lw3), 131072);
  prep_out2<<<128, 256, 0, stream>>>(o2w, (bf16*)P(o_o2p));
  float* sc1 = (float*)P(o_ss); float* sh1 = sc1 + 256;
  float* sc2 = sh1 + 256;       float* sh2 = sc2 + 256;
  prep_scsh<<<1, 256, 0, stream>>>(cb_[0], bng[0], bnb[0], bnm[0], bnv[0], sc1, sh1);
  prep_scsh<<<1, 256, 0, stream>>>(cb_[1], bng[1], bnb[1], bnm[1], bnv[1], sc2, sh2);
  prep_bkv<<<2, 256, 0, stream>>>(bk, bv, (float*)P(o_bkv));

  bf16* BA = (bf16*)P(o_BA);
  bf16* BH = (bf16*)P(o_BH);
  bf16* lfb[2] = { (bf16*)P(o_lfL), (bf16*)P(o_lfR) };

  // ---- merged front ----
  for (int hd = 0; hd < 2; hd++)
    gemm(feats[hd], P(o_w1t), nullptr, BA + (size_t)hd * NLF * DD,
         nullptr, nullptr, nullptr, NLF, 256, 512, 512, 1);      // A_F32
  gat_attn<<<2 * NBT, 256, 0, stream>>>(BA, ga[0], adj, BA, 0);
  gemm(BA, P(o_w2t), nullptr, BH, nullptr, nullptr, nullptr,
       2 * NLF, 256, 256, 256, 0);
  pad_zero<<<672, 256, 0, stream>>>(BA + DD);
  gat_attn<<<2 * NBT, 256, 0, stream>>>(BH, ga[1], adj, BA + DD, 1);
  gemm(BA, P(o_cw1), nullptr, BH + DD, nullptr, sc1, sh1,
       CONVM2, 256, 768, 256, 8 | 4 | 16);
  gemm(BH, P(o_cw2), nullptr, lfb[0], nullptr, sc2, sh2,
       CONVM2, 256, 768, 256, 8 | 4 | 32);

  // ---- cross-hand MHA (Q merged, KV per-pass, WO+pool merged) ----
  gemm(lfb[0], P(o_wq), nullptr, BA, bq, nullptr, nullptr, 2 * NLF, 256, 256, 256, 0);
  gemm(lfb[1], P(o_wk), nullptr, BH, P(o_bkv), nullptr, nullptr, NLF, 512, 256, 256, 0);
  mha_core2<<<NBT, 256, 0, stream>>>(BA, BH, BA);
  gemm(lfb[0], P(o_wk), nullptr, BH, P(o_bkv), nullptr, nullptr, NLF, 512, 256, 256, 0);
  mha_core2<<<NBT, 256, 0, stream>>>(BA + (size_t)NLF * DD, BH, BA + (size_t)NLF * DD);
  gemm(BA, P(o_wo), nullptr, BH, bo, nullptr, nullptr, 2 * NLF, 256, 256, 256, 0);
  pool2_kernel<<<2 * NBT, 256, 0, stream>>>(lfb[0], BH, (bf16*)P(o_le));

  // ---- BiLSTM ----
  float* xw = (float*)P(o_BH);
  gemm(P(o_le), P(o_lw0), xw, nullptr, nullptr, nullptr, nullptr,
       2 * NBT, 1024, 256, 256, 2);
  lstm_lds<<<32, 512, 0, stream>>>(xw, Lwhh[0][0], Lwhh[0][1],
      Lbih[0][0], Lbhh[0][0], Lbih[0][1], Lbhh[0][1],
      (bf16*)P(o_h1L), (bf16*)P(o_h1R));
  gemm(P(o_h1L), P(o_lw2), xw, nullptr, nullptr, nullptr, nullptr,
       2 * NBT, 1024, 256, 256, 2);
  lstm_lds<<<32, 512, 0, stream>>>(xw, Lwhh[1][0], Lwhh[1][1],
      Lbih[1][0], Lbhh[1][0], Lbih[1][1], Lbhh[1][1],
      (bf16*)P(o_hoL), (bf16*)P(o_hoR));

  // ---- heads ----
  gemm(P(o_hoL), P(o_o1w), nullptr, BA, o1b, nullptr, nullptr,
       2 * NBT, 256, 256, 256, 4);
  gemm(BA, P(o_o2p), d_out, nullptr, o2b, vis, nullptr,
       2 * NBT, 128, 256, 256, 64);
}

// Round 18
// 2107.551 us; speedup vs baseline: 1.0376x; 1.0012x over previous
//
#include <hip/hip_runtime.h>

typedef __bf16 bf16;
typedef bf16 bf16x8 __attribute__((ext_vector_type(8)));
typedef float f32x4 __attribute__((ext_vector_type(4)));
typedef _Float16 f16;
typedef f16 f16x8 __attribute__((ext_vector_type(8)));

#define NBT 4096      // B*T = 8*512
#define NJ 21
#define NLF 86016     // NBT*NJ (one hand)
#define DD 256
#define CONVM1 86352  // 168*514 (one hand)
#define CONVM2 172704 // both hands
#define SPAD 514
#define CROWS_ALL 173056  // 1 guard + 172704 + slack

// async global->LDS, 16B per lane; LDS dest is WAVE-UNIFORM base + lane*16
__device__ __forceinline__ void gload16(const bf16* g, bf16* l) {
  __builtin_amdgcn_global_load_lds(
      (const __attribute__((address_space(1))) unsigned int*)g,
      (__attribute__((address_space(3))) unsigned int*)l, 16, 0, 0);
}

// flags: 1=A_F32  2=OUT_F32(C32)  4=RELU  8=BNSS(sc/sh)  16=PADZ(conv layout)
//        32=LFOUT(conv row -> lf row, hand-aware)  64=FINAL(+bias,*vis->d_out)
// R18: R15 structure (BK=32, dbuf, counted vmcnt) + SWIZZLE ONLY (unbundling
// R16): phys_slot = logical_slot ^ ((row>>1)&3) on 64B rows. Read quad
// becomes 4(row&1) + (slot^((row>>1)&3)) -> 2 lanes/quad = conflict-free
// (was 8-way). Both sides: gload SOURCE col pre-swizzled (lane&3)^((lane>>3)&3)
// (chunk-independent: ch*16>>1 = 0 mod 4); f32-A staging writes swizzled;
// fragment reads XOR the same involution.
__global__ __launch_bounds__(256, 2) void gemm_bf16(
    const void* __restrict__ Av, const bf16* __restrict__ Bt,
    float* __restrict__ C32, bf16* __restrict__ Cout,
    const float* __restrict__ bias, const float* __restrict__ sc,
    const float* __restrict__ sh, int M, int N, int K, int lda, int flags)
{
  __shared__ __align__(16) bf16 As[2][128][32];
  __shared__ __align__(16) bf16 Bs[2][128][32];
  const int tid = threadIdx.x;
  const long m0 = (long)blockIdx.y * 128;
  const int n0 = blockIdx.x * 128;
  const int wave = tid >> 6, lane = tid & 63;
  const int wm = (wave & 1) * 64, wn = (wave >> 1) * 64;
  const int frow = lane & 15;
  const int crow = lane >> 2;
  const int scol = (((lane & 3) ^ ((lane >> 3) & 3)) << 3);  // swizzled source col
  const int fso  = (((lane >> 4) ^ ((lane >> 1) & 3)) << 4); // swizzled read byte-off
  const bf16* Ab = (const bf16*)Av;
  const float* Af = (const float*)Av;
  const int nk = K >> 5;
  const int ch0 = wave * 2, ch1 = ch0 + 1;
  const long arow0 = (m0 + ch0 * 16 + crow) * (long)lda + scol;
  const long arow1 = (m0 + ch1 * 16 + crow) * (long)lda + scol;
  const long brow0 = ((long)(n0 + ch0 * 16 + crow)) * K + scol;
  const long brow1 = ((long)(n0 + ch1 * 16 + crow)) * K + scol;
  const int lr = tid >> 1, lc = (tid & 1) * 16;   // f32-A staging map
  const int swzr = (lr >> 1) & 3;                 // staging row swizzle key

  auto stageA_f32 = [&](int buf, int k0) {
    const float* ap = Af + (m0 + lr) * (long)lda + (k0 + lc);
    bf16x8 t0, t1;
    #pragma unroll
    for (int u = 0; u < 8; u++) { t0[u] = (bf16)ap[u]; t1[u] = (bf16)ap[8 + u]; }
    const int s0 = (lc >> 3) ^ swzr, s1 = ((lc >> 3) + 1) ^ swzr;
    *(bf16x8*)((char*)&As[buf][lr][0] + (s0 << 4)) = t0;
    *(bf16x8*)((char*)&As[buf][lr][0] + (s1 << 4)) = t1;
  };

  f32x4 acc[4][4] = {};
  if (flags & 1) stageA_f32(0, 0);
  else {
    gload16(Ab + arow0, &As[0][ch0 * 16][0]);
    gload16(Ab + arow1, &As[0][ch1 * 16][0]);
  }
  gload16(Bt + brow0, &Bs[0][ch0 * 16][0]);
  gload16(Bt + brow1, &Bs[0][ch1 * 16][0]);

  for (int kt = 0; kt < nk; kt++) {
    const int cur = kt & 1;
    if (kt + 1 < nk) {
      const int k0 = (kt + 1) << 5;
      if (flags & 1) {
        stageA_f32(cur ^ 1, k0);
        gload16(Bt + brow0 + k0, &Bs[cur ^ 1][ch0 * 16][0]);
        gload16(Bt + brow1 + k0, &Bs[cur ^ 1][ch1 * 16][0]);
        asm volatile("s_waitcnt vmcnt(2) lgkmcnt(0)" ::: "memory");
      } else {
        gload16(Ab + arow0 + k0, &As[cur ^ 1][ch0 * 16][0]);
        gload16(Ab + arow1 + k0, &As[cur ^ 1][ch1 * 16][0]);
        gload16(Bt + brow0 + k0, &Bs[cur ^ 1][ch0 * 16][0]);
        gload16(Bt + brow1 + k0, &Bs[cur ^ 1][ch1 * 16][0]);
        asm volatile("s_waitcnt vmcnt(4) lgkmcnt(0)" ::: "memory");
      }
    } else {
      asm volatile("s_waitcnt vmcnt(0) lgkmcnt(0)" ::: "memory");
    }
    __builtin_amdgcn_sched_barrier(0);
    __builtin_amdgcn_s_barrier();
    __builtin_amdgcn_sched_barrier(0);
    bf16x8 af[4], bg[4];
    #pragma unroll
    for (int i = 0; i < 4; i++)
      af[i] = *(const bf16x8*)((const char*)&As[cur][wm + i * 16 + frow][0] + fso);
    #pragma unroll
    for (int j = 0; j < 4; j++)
      bg[j] = *(const bf16x8*)((const char*)&Bs[cur][wn + j * 16 + frow][0] + fso);
    #pragma unroll
    for (int i = 0; i < 4; i++)
      #pragma unroll
      for (int j = 0; j < 4; j++)
        acc[i][j] = __builtin_amdgcn_mfma_f32_16x16x32_bf16(af[i], bg[j], acc[i][j], 0, 0, 0);
    asm volatile("s_waitcnt lgkmcnt(0)" ::: "memory");
    __builtin_amdgcn_sched_barrier(0);
    __builtin_amdgcn_s_barrier();
    __builtin_amdgcn_sched_barrier(0);
  }
  const int col = lane & 15, rbase = (lane >> 4) * 4;
  #pragma unroll
  for (int i = 0; i < 4; i++) {
    #pragma unroll
    for (int j = 0; j < 4; j++) {
      const int nn = n0 + wn + j * 16 + col;
      #pragma unroll
      for (int r = 0; r < 4; r++) {
        const long mm = m0 + wm + i * 16 + rbase + r;
        if (mm >= M) continue;
        float v = acc[i][j][r];
        if (flags & 64) {            // FINAL: +o2b, *vis, f32 -> d_out[mm*63+nn]
          if (nn < 63) {
            float vv = (v + bias[nn]) * sc[(mm & (NBT - 1)) * 21 + nn / 3];
            C32[mm * 63 + nn] = vv;
          }
          continue;
        }
        if (flags & 2) { C32[mm * (long)N + nn] = v; continue; }
        if (flags & 8) v = v * sc[nn] + sh[nn];
        else if (bias) v += bias[nn];
        if (flags & 4) v = fmaxf(v, 0.f);
        if (flags & 16) {
          const int s = (int)(mm % SPAD);
          if (s == 0 || s == SPAD - 1) v = 0.f;
          Cout[mm * (long)N + nn] = (bf16)v;
        } else if (flags & 32) {
          const long hj = mm / SPAD; const int s = (int)(mm - hj * SPAD);
          if (s == 0 || s == SPAD - 1) continue;
          const int hand = (int)(hj / 168); const int lhj = (int)(hj - hand * 168);
          const int b = lhj / NJ; const int j2 = lhj - b * NJ;
          const long dst = (long)hand * NLF + ((long)b * 512 + (s - 1)) * NJ + j2;
          Cout[dst * (long)N + nn] = (bf16)v;
        } else {
          Cout[mm * (long)N + nn] = (bf16)v;
        }
      }
    }
  }
}

// ---------------- weight prep (f32 -> bf16) ----------------
__global__ void cvt_k(const float* __restrict__ s, bf16* __restrict__ d, long n) {
  long i = (long)blockIdx.x * 256 + threadIdx.x;
  if (i < n) d[i] = (bf16)s[i];
}
__global__ void prep_gatW(const float* __restrict__ W, bf16* __restrict__ Wt, int F) {
  long idx = (long)blockIdx.x * 256 + threadIdx.x;
  if (idx >= 256L * F) return;
  int n = (int)(idx / F), f = (int)(idx % F);
  Wt[idx] = (bf16)W[((long)(n >> 6) * F + f) * 64 + (n & 63)];
}
__global__ void prep_convw(const float* __restrict__ w, bf16* __restrict__ wp) {
  int idx = blockIdx.x * 256 + threadIdx.x;
  int n = idx / 768, k = idx % 768, tap = k >> 8, i = k & 255;
  wp[idx] = (bf16)w[(n * 256 + i) * 3 + tap];
}
__global__ void prep_out2(const float* __restrict__ w, bf16* __restrict__ wp) {
  int idx = blockIdx.x * 256 + threadIdx.x;
  wp[idx] = (idx < 63 * 256) ? (bf16)w[idx] : (bf16)0.f;
}
__global__ void prep_scsh(const float* __restrict__ cb, const float* __restrict__ g,
                          const float* __restrict__ be, const float* __restrict__ m,
                          const float* __restrict__ v, float* __restrict__ sc,
                          float* __restrict__ sh) {
  int c = threadIdx.x;
  float rs = rsqrtf(v[c] + 1e-5f) * g[c];
  sc[c] = rs; sh[c] = (cb[c] - m[c]) * rs + be[c];
}
__global__ void prep_bkv(const float* __restrict__ bk, const float* __restrict__ bv,
                         float* __restrict__ o) {
  int i = blockIdx.x * 256 + threadIdx.x;
  if (i >= 512) return;
  o[i] = (i < 256) ? bk[i] : bv[i - 256];
}
__global__ void pad_zero(bf16* __restrict__ convIn) {
  int idx = blockIdx.x * 256 + threadIdx.x;          // 336*2*256
  int hj = idx >> 9, s = ((idx >> 8) & 1) ? (SPAD - 1) : 0, c = idx & 255;
  convIn[((long)hj * SPAD + s) * DD + c] = (bf16)0.f;
}
__global__ void zero_out(float* __restrict__ o, long n) {
  long i = (long)blockIdx.x * 256 + threadIdx.x;
  if (i < n) o[i] = 0.f;
}

// ---------------- GAT attention (merged hands; in-place safe) ----------------
__global__ __launch_bounds__(256) void gat_attn(
    const bf16* __restrict__ Wh, const float* __restrict__ a,
    const float* __restrict__ adj, bf16* __restrict__ out, int convMode)
{
  const int bt = blockIdx.x, tid = threadIdx.x;
  __shared__ float whs[NJ][DD];
  __shared__ float s1[4][NJ], s2[4][NJ];
  __shared__ float att[4][NJ][NJ];
  const long base = (long)bt * NJ * DD;
  for (int i = tid; i < NJ * DD; i += 256)
    whs[i >> 8][i & 255] = (float)Wh[base + i];
  __syncthreads();
  if (tid < 4 * NJ) {
    const int h = tid / NJ, i = tid % NJ;
    float x1 = 0.f, x2 = 0.f;
    for (int d = 0; d < 64; d++) {
      const float w = whs[i][h * 64 + d];
      x1 += w * a[h * 128 + d];
      x2 += w * a[h * 128 + 64 + d];
    }
    s1[h][i] = x1; s2[h][i] = x2;
  }
  __syncthreads();
  for (int idx = tid; idx < 4 * NJ * NJ; idx += 256) {
    const int h = idx / (NJ * NJ), r = idx % (NJ * NJ), i = r / NJ, j = r % NJ;
    float e = s1[h][i] + s2[h][j];
    e = e > 0.f ? e : 0.2f * e;
    att[h][i][j] = (adj[i * NJ + j] > 0.f) ? e : -9e15f;
  }
  __syncthreads();
  if (tid < 4 * NJ) {
    const int h = tid / NJ, i = tid % NJ;
    float mx = -3e38f;
    for (int j = 0; j < NJ; j++) mx = fmaxf(mx, att[h][i][j]);
    float sum = 0.f;
    for (int j = 0; j < NJ; j++) { const float ex = __expf(att[h][i][j] - mx); att[h][i][j] = ex; sum += ex; }
    const float inv = 1.f / sum;
    for (int j = 0; j < NJ; j++) att[h][i][j] *= inv;
  }
  __syncthreads();
  const int hand = bt >> 12, b = (bt >> 9) & 7, t = bt & 511;
  for (int idx = tid; idx < NJ * DD; idx += 256) {
    const int i = idx >> 8, c = idx & 255, h = c >> 6;
    float s = 0.f;
    for (int j = 0; j < NJ; j++) s += att[h][i][j] * whs[j][c];
    s = s > 0.f ? s : (__expf(s) - 1.f);              // ELU
    const long row = convMode
        ? ((long)hand * CONVM1 + ((long)(b * NJ + i)) * SPAD + (t + 1))
        : ((long)bt * NJ + i);
    out[row * DD + c] = (bf16)s;
  }
}

// ---------------- MHA core (per bt block; O may alias Q; KV packed N=512) --
__global__ __launch_bounds__(256) void mha_core2(
    const bf16* __restrict__ Q, const bf16* __restrict__ KV,
    bf16* __restrict__ O)
{
  const int bt = blockIdx.x, tid = threadIdx.x;
  __shared__ bf16 qs[NJ][DD], ks[NJ][DD], vs[NJ][DD];
  __shared__ float att[4][NJ][NJ];
  const long baseq = (long)bt * NJ * DD;
  const long basekv = (long)bt * NJ * 512;
  for (int i = tid; i < NJ * DD; i += 256) {
    const int r = i >> 8, c = i & 255;
    qs[r][c] = Q[baseq + i];
    ks[r][c] = KV[basekv + r * 512 + c];
    vs[r][c] = KV[basekv + r * 512 + 256 + c];
  }
  __syncthreads();
  for (int idx = tid; idx < 4 * NJ * NJ; idx += 256) {
    const int h = idx / (NJ * NJ), r = idx % (NJ * NJ), i = r / NJ, j = r % NJ;
    float s = 0.f;
    for (int d = 0; d < 64; d++) s += (float)qs[i][h * 64 + d] * (float)ks[j][h * 64 + d];
    att[h][i][j] = s * 0.125f;
  }
  __syncthreads();
  if (tid < 4 * NJ) {
    const int h = tid / NJ, i = tid % NJ;
    float mx = -3e38f;
    for (int j = 0; j < NJ; j++) mx = fmaxf(mx, att[h][i][j]);
    float sum = 0.f;
    for (int j = 0; j < NJ; j++) { const float ex = __expf(att[h][i][j] - mx); att[h][i][j] = ex; sum += ex; }
    const float inv = 1.f / sum;
    for (int j = 0; j < NJ; j++) att[h][i][j] *= inv;
  }
  __syncthreads();
  for (int idx = tid; idx < NJ * DD; idx += 256) {
    const int i = idx >> 8, c = idx & 255, h = c >> 6;
    float s = 0.f;
    for (int j = 0; j < NJ; j++) s += att[h][i][j] * (float)vs[j][c];
    O[baseq + i * DD + c] = (bf16)s;
  }
}

// ---------------- residual + joint-mean pool (merged hands, grid 8192) -----
__global__ __launch_bounds__(256) void pool2_kernel(
    const bf16* __restrict__ lfBase, const bf16* __restrict__ ao,
    bf16* __restrict__ leBase)
{
  const int b = blockIdx.x, c = threadIdx.x;
  const int h = b >> 12, bt = b & (NBT - 1);
  const bf16* lfp = lfBase + ((long)(1 - h) * NLF + (long)bt * NJ) * DD;
  const bf16* aop = ao + ((long)b * NJ) * DD;
  float s = 0.f;
  for (int j = 0; j < NJ; j++)
    s += (float)lfp[j * DD + c] + 0.5f * (float)aop[j * DD + c];
  leBase[((long)(1 - h) * NBT + bt) * DD + c] = (bf16)(s * (1.f / 21.f));
}

// ---------------- persistent LSTM: weights in LDS (R15: 307us) -------------
#define REP16(X) X(0) X(1) X(2) X(3) X(4) X(5) X(6) X(7) X(8) X(9) X(10) X(11) \
  X(12) X(13) X(14) X(15)

#define LDS_FENCE() do { \
  asm volatile("s_waitcnt lgkmcnt(0)" ::: "memory"); \
  __builtin_amdgcn_sched_barrier(0); \
  __builtin_amdgcn_s_barrier(); \
  __builtin_amdgcn_sched_barrier(0); \
} while (0)

__global__ __launch_bounds__(512, 1) void lstm_lds(
    const float* __restrict__ xw,
    const float* __restrict__ whhF, const float* __restrict__ whhB,
    const float* __restrict__ bihF, const float* __restrict__ bhhF,
    const float* __restrict__ bihB, const float* __restrict__ bhhB,
    bf16* __restrict__ outL, bf16* __restrict__ outR)
{
  const int wg = blockIdx.x;
  const int hand = wg >> 4, dir = (wg >> 3) & 1, b = wg & 7;
  const int tid = threadIdx.x;
  const float* whh = dir ? whhB : whhF;

  __shared__ f16 whhs[512][136];   // 139,264 B -> 1 WG/CU
  __shared__ f16 hbuf[136];
  __shared__ float gsb[512];

  for (int i = tid; i < 512 * 128; i += 512)
    whhs[i >> 7][i & 127] = (f16)whh[i];
  if (tid < 136) hbuf[tid] = (f16)0.f;
  const float bias = (dir ? bihB : bihF)[tid] + (dir ? bhhB : bhhF)[tid];
  float c = 0.f;
  const float* xp = xw + ((long)hand * NBT + (long)b * 512) * 1024 + dir * 512;
  bf16* outp = hand ? outR : outL;
  const bool isG = (tid >> 7) == 2;
  float xv = xp[(long)(dir ? 511 : 0) * 1024 + tid];
  __syncthreads();

  const f16* wrow = &whhs[tid][0];
#define WRD(i) f16x8 w##i = *(const f16x8*)(wrow + (i) * 8);
  REP16(WRD)
#undef WRD

  for (int s = 0; s < 512; s++) {
    const int t = dir ? (511 - s) : s;
    const int tn = dir ? (510 - s) : (s + 1);
    float xnext = 0.f;
    if (s < 511) xnext = xp[(long)tn * 1024 + tid];
    float a0 = xv + bias, a1 = 0.f, a2 = 0.f, a3 = 0.f;
#define WDOT(i) { \
    const f16x8 hv = *(const f16x8*)(&hbuf[(i) * 8]); \
    a0 = __builtin_amdgcn_fdot2(__builtin_shufflevector(w##i, w##i, 0, 1), \
                                __builtin_shufflevector(hv, hv, 0, 1), a0, false); \
    a1 = __builtin_amdgcn_fdot2(__builtin_shufflevector(w##i, w##i, 2, 3), \
                                __builtin_shufflevector(hv, hv, 2, 3), a1, false); \
    a2 = __builtin_amdgcn_fdot2(__builtin_shufflevector(w##i, w##i, 4, 5), \
                                __builtin_shufflevector(hv, hv, 4, 5), a2, false); \
    a3 = __builtin_amdgcn_fdot2(__builtin_shufflevector(w##i, w##i, 6, 7), \
                                __builtin_shufflevector(hv, hv, 6, 7), a3, false); }
    REP16(WDOT)
#undef WDOT
    {   // phase A: per-gate transcendental by all 512 threads
      const float g = (a0 + a1) + (a2 + a3);
      gsb[tid] = isG ? (1.f - 2.f * __builtin_amdgcn_rcpf(1.f + __expf(2.f * g)))
                     : __builtin_amdgcn_rcpf(1.f + __expf(-g));
    }
    LDS_FENCE();
    if (tid < 128) {   // phase B: short combine chain
      const float si = gsb[tid],       sf = gsb[tid + 128];
      const float tg = gsb[tid + 256], so = gsb[tid + 384];
      c = sf * c + si * tg;
      const float tc = 1.f - 2.f * __builtin_amdgcn_rcpf(1.f + __expf(2.f * c));
      const float h = so * tc;
      hbuf[tid] = (f16)h;
      outp[((long)b * 512 + t) * 256 + dir * 128 + tid] = (bf16)h;
    }
    LDS_FENCE();
    xv = xnext;
  }
}

extern "C" void kernel_launch(void* const* d_in, const int* in_sizes, int n_in,
                              void* d_out, int out_size, void* d_ws, size_t ws_size,
                              hipStream_t stream) {
  (void)in_sizes; (void)n_in;
  const float* feats[2] = { (const float*)d_in[0], (const float*)d_in[1] };
  const float* adj  = (const float*)d_in[2];
  const float* vis  = (const float*)d_in[3];
  const float* gW[2] = { (const float*)d_in[4], (const float*)d_in[6] };
  const float* ga[2] = { (const float*)d_in[5], (const float*)d_in[7] };
  const float* cw_[2] = { (const float*)d_in[8],  (const float*)d_in[10] };
  const float* cb_[2] = { (const float*)d_in[9],  (const float*)d_in[11] };
  const float* bng[2] = { (const float*)d_in[12], (const float*)d_in[16] };
  const float* bnb[2] = { (const float*)d_in[13], (const float*)d_in[17] };
  const float* bnm[2] = { (const float*)d_in[14], (const float*)d_in[18] };
  const float* bnv[2] = { (const float*)d_in[15], (const float*)d_in[19] };
  const float* wq = (const float*)d_in[20], *wk = (const float*)d_in[21];
  const float* wv = (const float*)d_in[22], *wo = (const float*)d_in[23];
  const float* bq = (const float*)d_in[24], *bk = (const float*)d_in[25];
  const float* bv = (const float*)d_in[26], *bo = (const float*)d_in[27];
  const float* Lwih[2][2] = { { (const float*)d_in[28], (const float*)d_in[32] },
                              { (const float*)d_in[36], (const float*)d_in[40] } };
  const float* Lwhh[2][2] = { { (const float*)d_in[29], (const float*)d_in[33] },
                              { (const float*)d_in[37], (const float*)d_in[41] } };
  const float* Lbih[2][2] = { { (const float*)d_in[30], (const float*)d_in[34] },
                              { (const float*)d_in[38], (const float*)d_in[42] } };
  const float* Lbhh[2][2] = { { (const float*)d_in[31], (const float*)d_in[35] },
                              { (const float*)d_in[39], (const float*)d_in[43] } };
  const float* o1w = (const float*)d_in[44], *o1b = (const float*)d_in[45];
  const float* o2w = (const float*)d_in[46], *o2b = (const float*)d_in[47];

  char* base = (char*)d_ws;
  size_t off = 0;
  auto alloc = [&](size_t b) { size_t r = off; off += (b + 1023) & ~(size_t)1023; return r; };
  const size_t SZ_BIG = (size_t)CROWS_ALL * DD * 2;   // 88.6 MB
  const size_t SZ_BT  = (size_t)NBT * DD * 2;         // 2.10 MB
  const size_t o_w1t = alloc((size_t)256 * 512 * 2);
  const size_t o_w2t = alloc((size_t)256 * 256 * 2);
  const size_t o_cw1 = alloc((size_t)256 * 768 * 2);
  const size_t o_cw2 = alloc((size_t)256 * 768 * 2);
  const size_t o_wq  = alloc((size_t)256 * 256 * 2);
  const size_t o_wk  = alloc((size_t)256 * 256 * 2);   // wk|wv contiguous
  const size_t o_wv  = alloc((size_t)256 * 256 * 2);
  const size_t o_wo  = alloc((size_t)256 * 256 * 2);
  const size_t o_o1w = alloc((size_t)256 * 256 * 2);
  const size_t o_o2p = alloc((size_t)128 * 256 * 2);
  const size_t o_lw0 = alloc((size_t)512 * 256 * 2);   // lw0|lw1 contiguous
  const size_t o_lw1 = alloc((size_t)512 * 256 * 2);
  const size_t o_lw2 = alloc((size_t)512 * 256 * 2);   // lw2|lw3 contiguous
  const size_t o_lw3 = alloc((size_t)512 * 256 * 2);
  const size_t o_ss  = alloc((size_t)4 * 256 * 4);
  const size_t o_bkv = alloc((size_t)512 * 4);
  const size_t o_BA  = alloc(SZ_BIG);
  const size_t o_BH  = alloc(SZ_BIG);
  const size_t o_lfL = alloc((size_t)NLF * DD * 2);   // lfL|lfR contiguous
  const size_t o_lfR = alloc((size_t)NLF * DD * 2);
  const size_t o_le  = alloc(SZ_BT);   // le|re contiguous
  const size_t o_re  = alloc(SZ_BT);
  const size_t o_h1L = alloc(SZ_BT);   // h1L|h1R contiguous
  const size_t o_h1R = alloc(SZ_BT);
  const size_t o_hoL = alloc(SZ_BT);   // hoL|hoR contiguous
  const size_t o_hoR = alloc(SZ_BT);
  const size_t NEED = off;
  if (ws_size < NEED) {
    zero_out<<<(out_size + 255) / 256, 256, 0, stream>>>((float*)d_out, out_size);
    return;
  }
  auto P = [&](size_t o_) { return (void*)(base + o_); };

  auto gemm = [&](const void* A, const void* Bt, void* c32, void* co,
                  const void* bias_, const void* sc_, const void* sh_,
                  long M, int N, int K, int lda, int flags) {
    dim3 g((unsigned)(N / 128), (unsigned)((M + 127) / 128));
    gemm_bf16<<<g, 256, 0, stream>>>(A, (const bf16*)Bt, (float*)c32, (bf16*)co,
                                     (const float*)bias_, (const float*)sc_,
                                     (const float*)sh_, (int)M, N, K, lda, flags);
  };
  auto cvt = [&](const float* s, void* d, long n) {
    cvt_k<<<(unsigned)((n + 255) / 256), 256, 0, stream>>>(s, (bf16*)d, n);
  };

  // ---- weight prep ----
  prep_gatW<<<512, 256, 0, stream>>>(gW[0], (bf16*)P(o_w1t), 512);
  prep_gatW<<<256, 256, 0, stream>>>(gW[1], (bf16*)P(o_w2t), 256);
  prep_convw<<<768, 256, 0, stream>>>(cw_[0], (bf16*)P(o_cw1));
  prep_convw<<<768, 256, 0, stream>>>(cw_[1], (bf16*)P(o_cw2));
  cvt(wq, P(o_wq), 65536); cvt(wk, P(o_wk), 65536);
  cvt(wv, P(o_wv), 65536); cvt(wo, P(o_wo), 65536);
  cvt(o1w, P(o_o1w), 65536);
  cvt(Lwih[0][0], P(o_lw0), 131072); cvt(Lwih[0][1], P(o_lw1), 131072);
  cvt(Lwih[1][0], P(o_lw2), 131072); cvt(Lwih[1][1], P(o_lw3), 131072);
  prep_out2<<<128, 256, 0, stream>>>(o2w, (bf16*)P(o_o2p));
  float* sc1 = (float*)P(o_ss); float* sh1 = sc1 + 256;
  float* sc2 = sh1 + 256;       float* sh2 = sc2 + 256;
  prep_scsh<<<1, 256, 0, stream>>>(cb_[0], bng[0], bnb[0], bnm[0], bnv[0], sc1, sh1);
  prep_scsh<<<1, 256, 0, stream>>>(cb_[1], bng[1], bnb[1], bnm[1], bnv[1], sc2, sh2);
  prep_bkv<<<2, 256, 0, stream>>>(bk, bv, (float*)P(o_bkv));

  bf16* BA = (bf16*)P(o_BA);
  bf16* BH = (bf16*)P(o_BH);
  bf16* lfb[2] = { (bf16*)P(o_lfL), (bf16*)P(o_lfR) };

  // ---- merged front ----
  for (int hd = 0; hd < 2; hd++)
    gemm(feats[hd], P(o_w1t), nullptr, BA + (size_t)hd * NLF * DD,
         nullptr, nullptr, nullptr, NLF, 256, 512, 512, 1);      // A_F32
  gat_attn<<<2 * NBT, 256, 0, stream>>>(BA, ga[0], adj, BA, 0);
  gemm(BA, P(o_w2t), nullptr, BH, nullptr, nullptr, nullptr,
       2 * NLF, 256, 256, 256, 0);
  pad_zero<<<672, 256, 0, stream>>>(BA + DD);
  gat_attn<<<2 * NBT, 256, 0, stream>>>(BH, ga[1], adj, BA + DD, 1);
  gemm(BA, P(o_cw1), nullptr, BH + DD, nullptr, sc1, sh1,
       CONVM2, 256, 768, 256, 8 | 4 | 16);
  gemm(BH, P(o_cw2), nullptr, lfb[0], nullptr, sc2, sh2,
       CONVM2, 256, 768, 256, 8 | 4 | 32);

  // ---- cross-hand MHA (Q merged, KV per-pass, WO+pool merged) ----
  gemm(lfb[0], P(o_wq), nullptr, BA, bq, nullptr, nullptr, 2 * NLF, 256, 256, 256, 0);
  gemm(lfb[1], P(o_wk), nullptr, BH, P(o_bkv), nullptr, nullptr, NLF, 512, 256, 256, 0);
  mha_core2<<<NBT, 256, 0, stream>>>(BA, BH, BA);
  gemm(lfb[0], P(o_wk), nullptr, BH, P(o_bkv), nullptr, nullptr, NLF, 512, 256, 256, 0);
  mha_core2<<<NBT, 256, 0, stream>>>(BA + (size_t)NLF * DD, BH, BA + (size_t)NLF * DD);
  gemm(BA, P(o_wo), nullptr, BH, bo, nullptr, nullptr, 2 * NLF, 256, 256, 256, 0);
  pool2_kernel<<<2 * NBT, 256, 0, stream>>>(lfb[0], BH, (bf16*)P(o_le));

  // ---- BiLSTM ----
  float* xw = (float*)P(o_BH);
  gemm(P(o_le), P(o_lw0), xw, nullptr, nullptr, nullptr, nullptr,
       2 * NBT, 1024, 256, 256, 2);
  lstm_lds<<<32, 512, 0, stream>>>(xw, Lwhh[0][0], Lwhh[0][1],
      Lbih[0][0], Lbhh[0][0], Lbih[0][1], Lbhh[0][1],
      (bf16*)P(o_h1L), (bf16*)P(o_h1R));
  gemm(P(o_h1L), P(o_lw2), xw, nullptr, nullptr, nullptr, nullptr,
       2 * NBT, 1024, 256, 256, 2);
  lstm_lds<<<32, 512, 0, stream>>>(xw, Lwhh[1][0], Lwhh[1][1],
      Lbih[1][0], Lbhh[1][0], Lbih[1][1], Lbhh[1][1],
      (bf16*)P(o_hoL), (bf16*)P(o_hoR));

  // ---- heads ----
  gemm(P(o_hoL), P(o_o1w), nullptr, BA, o1b, nullptr, nullptr,
       2 * NBT, 256, 256, 256, 4);
  gemm(BA, P(o_o2p), d_out, nullptr, o2b, vis, nullptr,
       2 * NBT, 128, 256, 256, 64);
}